// Round 5
// baseline (5837.474 us; speedup 1.0000x reference)
//
#include <hip/hip_runtime.h>

typedef _Float16 f16;
typedef _Float16 f16x2 __attribute__((ext_vector_type(2)));
typedef _Float16 f16x8 __attribute__((ext_vector_type(8)));
typedef float    f32x4 __attribute__((ext_vector_type(4)));

#define NSTEP 2048
#define HID   512
#define BATCH 32
#define SEQL  2048

// v_dot2_f32_f16: 2 f16 MACs, f32 accumulate.
#if __has_builtin(__builtin_amdgcn_fdot2)
#define FDOT2(a, b, c) __builtin_amdgcn_fdot2((a), (b), (c), false)
#else
static __device__ __forceinline__ float FDOT2(f16x2 a, f16x2 b, float c) {
    // folds to v_fma_mix_f32 pairs (f32-rate) — still beats 16x-redundant MFMA
    return c + (float)a[0] * (float)b[0] + (float)a[1] * (float)b[1];
}
#endif

// ---------------------------------------------------------------------------
// Phase 1: xproj[m][n] = sum_k x[m][k] * Wxh[n][k] + (bxh+bhh+bh)[n], f16 out
// M=65536, N=512, K=512.  Block: 64 rows x 512 cols, 256 threads (4 waves).
// ---------------------------------------------------------------------------
#define P1_AS 40   // padded lds stride (f16) to spread banks; 80B = 16B-aligned

__global__ __launch_bounds__(256, 2) void xproj_kernel(
    const float* __restrict__ x, const float* __restrict__ Wxh,
    const float* __restrict__ bxh, const float* __restrict__ bhh,
    const float* __restrict__ bh, f16* __restrict__ xp)
{
    __shared__ __align__(16) f16 As[64 * P1_AS];
    __shared__ __align__(16) f16 Bs[512 * P1_AS];

    const int t = threadIdx.x;
    const int wave = t >> 6, lane = t & 63;
    const size_t mbase = (size_t)blockIdx.x * 64;

    f32x4 acc[4][8];
#pragma unroll
    for (int i = 0; i < 4; i++)
#pragma unroll
        for (int j = 0; j < 8; j++) acc[i][j] = (f32x4){0.f, 0.f, 0.f, 0.f};

    const int r_st = t >> 2;          // 0..63
    const int koff = (t & 3) * 8;     // 0,8,16,24

    for (int k0 = 0; k0 < 512; k0 += 32) {
        __syncthreads();
        // stage A: 64 rows x 32 k (f32 -> f16)
        {
            const float* src = x + (mbase + r_st) * 512 + k0 + koff;
            float4 a0 = *(const float4*)src;
            float4 a1 = *(const float4*)(src + 4);
            f16x8 h;
            h[0] = (f16)a0.x; h[1] = (f16)a0.y; h[2] = (f16)a0.z; h[3] = (f16)a0.w;
            h[4] = (f16)a1.x; h[5] = (f16)a1.y; h[6] = (f16)a1.z; h[7] = (f16)a1.w;
            *(f16x8*)&As[r_st * P1_AS + koff] = h;
        }
        // stage B: 512 rows(n) x 32 k, 8 passes
#pragma unroll
        for (int i = 0; i < 8; i++) {
            int n = r_st + i * 64;
            const float* src = Wxh + (size_t)n * 512 + k0 + koff;
            float4 b0 = *(const float4*)src;
            float4 b1 = *(const float4*)(src + 4);
            f16x8 h;
            h[0] = (f16)b0.x; h[1] = (f16)b0.y; h[2] = (f16)b0.z; h[3] = (f16)b0.w;
            h[4] = (f16)b1.x; h[5] = (f16)b1.y; h[6] = (f16)b1.z; h[7] = (f16)b1.w;
            *(f16x8*)&Bs[n * P1_AS + koff] = h;
        }
        __syncthreads();

        // A frags: row = rt*16 + (lane&15), k = (lane>>4)*8 + j
        f16x8 af[4];
#pragma unroll
        for (int rt = 0; rt < 4; rt++)
            af[rt] = *(const f16x8*)&As[(rt * 16 + (lane & 15)) * P1_AS + (lane >> 4) * 8];
#pragma unroll
        for (int ct = 0; ct < 8; ct++) {
            f16x8 bf = *(const f16x8*)&Bs[((wave * 8 + ct) * 16 + (lane & 15)) * P1_AS + (lane >> 4) * 8];
#pragma unroll
            for (int rt = 0; rt < 4; rt++)
                acc[rt][ct] = __builtin_amdgcn_mfma_f32_16x16x32_f16(af[rt], bf, acc[rt][ct], 0, 0, 0);
        }
    }

    // epilogue: D col = lane&15, row = (lane>>4)*4 + r
#pragma unroll
    for (int ct = 0; ct < 8; ct++) {
        int n = wave * 128 + ct * 16 + (lane & 15);
        float bias = bxh[n] + bhh[n] + bh[n];
#pragma unroll
        for (int rt = 0; rt < 4; rt++) {
#pragma unroll
            for (int r = 0; r < 4; r++) {
                size_t m = mbase + rt * 16 + (lane >> 4) * 4 + r;
                xp[m * 512 + n] = (f16)(acc[rt][ct][r] + bias);
            }
        }
    }
}

// ---------------------------------------------------------------------------
// Phase 2: recurrence.  1 block (512 thr, 8 waves) per batch, 32 blocks
// (1 block/CU).  Hybrid MFMA/VALU column split (r3 post-mortem: the all-MFMA
// structure is MFMA-issue-roofline-bound at 2483 cyc/step with 16x redundant
// work; VALU pipe sits idle and can do the job in less).
//   MFMA: cols [0,128)  — 1 tile/wave, 16 wreg frags, ~620 cyc/step pipe time
//   VALU: cols [128,512) — v_dot2_f32_f16, weights in VGPRs (3 cols/lane,
//         lane's k-set = its MFMA-fragment k-set), ~770 cyc/step VALU time,
//         co-issued with MFMA (m114).  h LDS read feeds BOTH pipes.
//   k-partials reduced across lane quarters via shfl_xor(16), shfl_xor(32).
// Register budget: weights are 256 VGPR/thread (structure-invariant), so
// __launch_bounds__(512, 1): allocator may use up to 512 — no spill, and
// occupancy is unaffected (grid is 1 block/CU regardless).
// ---------------------------------------------------------------------------
__global__ __launch_bounds__(512, 1) void rnn_kernel(
    const float* __restrict__ Whh, const f16* __restrict__ xp,
    f16* __restrict__ hfin)
{
    __shared__ __align__(16) f16 hbuf[2][HID];

    const int t = threadIdx.x;
    const int wave = t >> 6, lane = t & 63;
    const int b = blockIdx.x;

    const int c_in = lane & 15;              // fragment column
    const int q    = lane >> 4;              // k-quarter 0..3
    const int k8   = q * 8;                  // fragment k base

    // ---- MFMA weights: tile = wave, cols n = wave*16 + c_in (one-time) ----
    f16x8 wreg[16];
    {
        const float* wrow = Whh + (size_t)(wave * 16 + c_in) * 512;
#pragma unroll
        for (int kf = 0; kf < 16; kf++) {
            float4 w0 = *(const float4*)(wrow + kf * 32 + k8);
            float4 w1 = *(const float4*)(wrow + kf * 32 + k8 + 4);
            f16x8 h;
            h[0] = (f16)w0.x; h[1] = (f16)w0.y; h[2] = (f16)w0.z; h[3] = (f16)w0.w;
            h[4] = (f16)w1.x; h[5] = (f16)w1.y; h[6] = (f16)w1.z; h[7] = (f16)w1.w;
            wreg[kf] = h;
        }
    }
    // ---- VALU weights: 3 cols/lane, this lane's strided k-set (one-time) ----
    // col c: n = 128 + wave*48 + c*16 + c_in;  elems Whh[n][kf*32 + k8 + i]
    const int nv0 = 128 + wave * 48 + c_in;
    const int nv1 = nv0 + 16;
    const int nv2 = nv0 + 32;
    f16x8 w0r[16], w1r[16], w2r[16];
#pragma unroll
    for (int kf = 0; kf < 16; kf++) {
        const float* p0 = Whh + (size_t)nv0 * 512 + kf * 32 + k8;
        const float* p1 = Whh + (size_t)nv1 * 512 + kf * 32 + k8;
        const float* p2 = Whh + (size_t)nv2 * 512 + kf * 32 + k8;
        float4 a0 = *(const float4*)p0, a1 = *(const float4*)(p0 + 4);
        float4 b0 = *(const float4*)p1, b1 = *(const float4*)(p1 + 4);
        float4 c0 = *(const float4*)p2, c1 = *(const float4*)(p2 + 4);
        f16x8 ha, hb, hc;
        ha[0]=(f16)a0.x; ha[1]=(f16)a0.y; ha[2]=(f16)a0.z; ha[3]=(f16)a0.w;
        ha[4]=(f16)a1.x; ha[5]=(f16)a1.y; ha[6]=(f16)a1.z; ha[7]=(f16)a1.w;
        hb[0]=(f16)b0.x; hb[1]=(f16)b0.y; hb[2]=(f16)b0.z; hb[3]=(f16)b0.w;
        hb[4]=(f16)b1.x; hb[5]=(f16)b1.y; hb[6]=(f16)b1.z; hb[7]=(f16)b1.w;
        hc[0]=(f16)c0.x; hc[1]=(f16)c0.y; hc[2]=(f16)c0.z; hc[3]=(f16)c0.w;
        hc[4]=(f16)c1.x; hc[5]=(f16)c1.y; hc[6]=(f16)c1.z; hc[7]=(f16)c1.w;
        w0r[kf] = ha; w1r[kf] = hb; w2r[kf] = hc;
    }

    hbuf[0][t & (HID - 1)] = (f16)0.f;       // h0 = 0
    __syncthreads();

    const size_t xbase = (size_t)b * SEQL * 512;
    const int nm = wave * 16 + c_in;         // MFMA output col for this lane

    // dist-1 float prefetch (r0-proven pattern), 4 output cols per lane
    float xm = (float)xp[xbase + nm];
    float x0 = (float)xp[xbase + nv0];
    float x1 = (float)xp[xbase + nv1];
    float x2 = (float)xp[xbase + nv2];

    for (int s = 0; s < NSTEP; s++) {
        const f16* cur = hbuf[s & 1];
        f16*       nxt = hbuf[(s & 1) ^ 1];
        size_t nb = xbase + (size_t)((s + 1 < NSTEP) ? s + 1 : s) * 512;
        float xmn = (float)xp[nb + nm];
        float x0n = (float)xp[nb + nv0];
        float x1n = (float)xp[nb + nv1];
        float x2n = (float)xp[nb + nv2];

        f32x4 acc = (f32x4){0.f, 0.f, 0.f, 0.f};
        float s0 = 0.f, s1 = 0.f, s2 = 0.f;
#pragma unroll
        for (int kf = 0; kf < 16; kf++) {
            f16x8 av = *(const f16x8*)&cur[kf * 32 + k8];   // broadcast read
            acc = __builtin_amdgcn_mfma_f32_16x16x32_f16(av, wreg[kf], acc, 0, 0, 0);
            f16x8 wa = w0r[kf], wb = w1r[kf], wc = w2r[kf];
            // literal pair indices (shufflevector requires ICE); each f16x2
            // is a natural VGPR subregister of the f16x8 — zero-cost extract
#define RNN_DOT3(P)                                                            \
            do {                                                               \
                f16x2 hp = __builtin_shufflevector(av, av, 2*(P), 2*(P)+1);    \
                s0 = FDOT2(hp, __builtin_shufflevector(wa, wa, 2*(P), 2*(P)+1), s0); \
                s1 = FDOT2(hp, __builtin_shufflevector(wb, wb, 2*(P), 2*(P)+1), s1); \
                s2 = FDOT2(hp, __builtin_shufflevector(wc, wc, 2*(P), 2*(P)+1), s2); \
            } while (0)
            RNN_DOT3(0); RNN_DOT3(1); RNN_DOT3(2); RNN_DOT3(3);
#undef RNN_DOT3
        }
        // reduce VALU k-partials across the 4 lane-quarters (bits 4,5)
        s0 += __shfl_xor(s0, 16, 64); s0 += __shfl_xor(s0, 32, 64);
        s1 += __shfl_xor(s1, 16, 64); s1 += __shfl_xor(s1, 32, 64);
        s2 += __shfl_xor(s2, 16, 64); s2 += __shfl_xor(s2, 32, 64);

        if (q == 0) {
            float vm = acc[0] + xm;          // all D rows identical; row 0
            float v0 = s0 + x0;
            float v1 = s1 + x1;
            float v2 = s2 + x2;
            vm = 1.f - 2.f / (__expf(2.f * vm) + 1.f);
            v0 = 1.f - 2.f / (__expf(2.f * v0) + 1.f);
            v1 = 1.f - 2.f / (__expf(2.f * v1) + 1.f);
            v2 = 1.f - 2.f / (__expf(2.f * v2) + 1.f);
            nxt[nm]  = (f16)vm;
            nxt[nv0] = (f16)v0;
            nxt[nv1] = (f16)v1;
            nxt[nv2] = (f16)v2;
        }
        xm = xmn; x0 = x0n; x1 = x1n; x2 = x2n;
        __syncthreads();
    }
    // NSTEP even -> final h sits in hbuf[0]
    hfin[(size_t)b * 512 + t] = hbuf[0][t & (HID - 1)];
}

// ---------------------------------------------------------------------------
// Phase 3: out[b][o] = sum_k h[b][k] * Wfc[o][k] + bfc[o]  (fp32 out)
// 32 blocks x 16 o-slice, 256 threads; h staged in padded LDS.
// ---------------------------------------------------------------------------
#define P3_HS 520  // padded stride (f16); 1040B is 16B-aligned

__global__ __launch_bounds__(256, 2) void fc_kernel(
    const f16* __restrict__ hfin, const float* __restrict__ Wfc,
    const float* __restrict__ bfc, float* __restrict__ out)
{
    __shared__ __align__(16) f16 hs[BATCH * P3_HS];
    const int t = threadIdx.x;
    // stage h (coalesced 2B loads, scattered padded LDS writes — one-time)
    for (int i = 0; i < 64; i++) {
        int e = i * 256 + t;                 // 0..16383
        hs[(e >> 9) * P3_HS + (e & 511)] = hfin[e];
    }
    __syncthreads();

    const int bidx = t & 31;
    const int oi = t >> 5;                   // 0..7
    const int o0 = blockIdx.x * 16;
    const int oA = o0 + oi, oB = o0 + oi + 8;
    const float* wA = Wfc + (size_t)oA * 512;
    const float* wB = Wfc + (size_t)oB * 512;

    float sA = 0.f, sB = 0.f;
#pragma unroll 4
    for (int kb = 0; kb < 64; kb++) {
        f16x8 hv = *(const f16x8*)&hs[bidx * P3_HS + kb * 8];
        float4 wa0 = *(const float4*)(wA + kb * 8);
        float4 wa1 = *(const float4*)(wA + kb * 8 + 4);
        float4 wb0 = *(const float4*)(wB + kb * 8);
        float4 wb1 = *(const float4*)(wB + kb * 8 + 4);
        float h0 = (float)hv[0], h1 = (float)hv[1], h2 = (float)hv[2], h3 = (float)hv[3];
        float h4 = (float)hv[4], h5 = (float)hv[5], h6 = (float)hv[6], h7 = (float)hv[7];
        sA += wa0.x*h0 + wa0.y*h1 + wa0.z*h2 + wa0.w*h3 + wa1.x*h4 + wa1.y*h5 + wa1.z*h6 + wa1.w*h7;
        sB += wb0.x*h0 + wb0.y*h1 + wb0.z*h2 + wb0.w*h3 + wb1.x*h4 + wb1.y*h5 + wb1.z*h6 + wb1.w*h7;
    }
    out[(size_t)bidx * 512 + oA] = sA + bfc[oA];
    out[(size_t)bidx * 512 + oB] = sB + bfc[oB];
}

// ---------------------------------------------------------------------------
extern "C" void kernel_launch(void* const* d_in, const int* in_sizes, int n_in,
                              void* d_out, int out_size, void* d_ws, size_t ws_size,
                              hipStream_t stream) {
    const float* x    = (const float*)d_in[0];
    const float* Wxh  = (const float*)d_in[1];
    const float* bxh  = (const float*)d_in[2];
    const float* Whh  = (const float*)d_in[3];
    const float* bhh  = (const float*)d_in[4];
    const float* bh   = (const float*)d_in[5];
    const float* Wfc  = (const float*)d_in[6];
    const float* bfc  = (const float*)d_in[7];
    float* outp = (float*)d_out;

    f16* xp   = (f16*)d_ws;                                   // 64 MiB
    f16* hfin = (f16*)((char*)d_ws + (size_t)BATCH * SEQL * 512 * 2);

    xproj_kernel<<<(BATCH * SEQL) / 64, 256, 0, stream>>>(x, Wxh, bxh, bhh, bh, xp);
    rnn_kernel<<<BATCH, 512, 0, stream>>>(Whh, xp, hfin);
    fc_kernel<<<32, 256, 0, stream>>>(hfin, Wfc, bfc, outp);
}

// Round 6
// 3575.077 us; speedup vs baseline: 1.6328x; 1.6328x over previous
//
#include <hip/hip_runtime.h>

typedef _Float16 f16;
typedef _Float16 f16x2 __attribute__((ext_vector_type(2)));
typedef _Float16 f16x8 __attribute__((ext_vector_type(8)));
typedef float    f32x4 __attribute__((ext_vector_type(4)));

#define NSTEP 2048
#define HID   512
#define BATCH 32
#define SEQL  2048

// v_dot2_f32_f16: 2 f16 MACs, f32 accumulate.
#if __has_builtin(__builtin_amdgcn_fdot2)
#define FDOT2(a, b, c) __builtin_amdgcn_fdot2((a), (b), (c), false)
#else
static __device__ __forceinline__ float FDOT2(f16x2 a, f16x2 b, float c) {
    return c + (float)a[0] * (float)b[0] + (float)a[1] * (float)b[1];
}
#endif

// 8 f16 MACs = 4 fdot2, literal pair indices (shufflevector needs ICE).
#define RNN_DOT8(AV, W, S)                                                  \
    do {                                                                    \
        S = FDOT2(__builtin_shufflevector(AV, AV, 0, 1),                    \
                  __builtin_shufflevector(W, W, 0, 1), S);                  \
        S = FDOT2(__builtin_shufflevector(AV, AV, 2, 3),                    \
                  __builtin_shufflevector(W, W, 2, 3), S);                  \
        S = FDOT2(__builtin_shufflevector(AV, AV, 4, 5),                    \
                  __builtin_shufflevector(W, W, 4, 5), S);                  \
        S = FDOT2(__builtin_shufflevector(AV, AV, 6, 7),                    \
                  __builtin_shufflevector(W, W, 6, 7), S);                  \
    } while (0)

// ---------------------------------------------------------------------------
// Phase 1: xproj[m][n] = sum_k x[m][k] * Wxh[n][k] + (bxh+bhh+bh)[n], f16 out
// M=65536, N=512, K=512.  Block: 64 rows x 512 cols, 256 threads (4 waves).
// ---------------------------------------------------------------------------
#define P1_AS 40   // padded lds stride (f16) to spread banks; 80B = 16B-aligned

__global__ __launch_bounds__(256, 2) void xproj_kernel(
    const float* __restrict__ x, const float* __restrict__ Wxh,
    const float* __restrict__ bxh, const float* __restrict__ bhh,
    const float* __restrict__ bh, f16* __restrict__ xp)
{
    __shared__ __align__(16) f16 As[64 * P1_AS];
    __shared__ __align__(16) f16 Bs[512 * P1_AS];

    const int t = threadIdx.x;
    const int wave = t >> 6, lane = t & 63;
    const size_t mbase = (size_t)blockIdx.x * 64;

    f32x4 acc[4][8];
#pragma unroll
    for (int i = 0; i < 4; i++)
#pragma unroll
        for (int j = 0; j < 8; j++) acc[i][j] = (f32x4){0.f, 0.f, 0.f, 0.f};

    const int r_st = t >> 2;          // 0..63
    const int koff = (t & 3) * 8;     // 0,8,16,24

    for (int k0 = 0; k0 < 512; k0 += 32) {
        __syncthreads();
        // stage A: 64 rows x 32 k (f32 -> f16)
        {
            const float* src = x + (mbase + r_st) * 512 + k0 + koff;
            float4 a0 = *(const float4*)src;
            float4 a1 = *(const float4*)(src + 4);
            f16x8 h;
            h[0] = (f16)a0.x; h[1] = (f16)a0.y; h[2] = (f16)a0.z; h[3] = (f16)a0.w;
            h[4] = (f16)a1.x; h[5] = (f16)a1.y; h[6] = (f16)a1.z; h[7] = (f16)a1.w;
            *(f16x8*)&As[r_st * P1_AS + koff] = h;
        }
        // stage B: 512 rows(n) x 32 k, 8 passes
#pragma unroll
        for (int i = 0; i < 8; i++) {
            int n = r_st + i * 64;
            const float* src = Wxh + (size_t)n * 512 + k0 + koff;
            float4 b0 = *(const float4*)src;
            float4 b1 = *(const float4*)(src + 4);
            f16x8 h;
            h[0] = (f16)b0.x; h[1] = (f16)b0.y; h[2] = (f16)b0.z; h[3] = (f16)b0.w;
            h[4] = (f16)b1.x; h[5] = (f16)b1.y; h[6] = (f16)b1.z; h[7] = (f16)b1.w;
            *(f16x8*)&Bs[n * P1_AS + koff] = h;
        }
        __syncthreads();

        // A frags: row = rt*16 + (lane&15), k = (lane>>4)*8 + j
        f16x8 af[4];
#pragma unroll
        for (int rt = 0; rt < 4; rt++)
            af[rt] = *(const f16x8*)&As[(rt * 16 + (lane & 15)) * P1_AS + (lane >> 4) * 8];
#pragma unroll
        for (int ct = 0; ct < 8; ct++) {
            f16x8 bf = *(const f16x8*)&Bs[((wave * 8 + ct) * 16 + (lane & 15)) * P1_AS + (lane >> 4) * 8];
#pragma unroll
            for (int rt = 0; rt < 4; rt++)
                acc[rt][ct] = __builtin_amdgcn_mfma_f32_16x16x32_f16(af[rt], bf, acc[rt][ct], 0, 0, 0);
        }
    }

    // epilogue: D col = lane&15, row = (lane>>4)*4 + r
#pragma unroll
    for (int ct = 0; ct < 8; ct++) {
        int n = wave * 128 + ct * 16 + (lane & 15);
        float bias = bxh[n] + bhh[n] + bh[n];
#pragma unroll
        for (int rt = 0; rt < 4; rt++) {
#pragma unroll
            for (int r = 0; r < 4; r++) {
                size_t m = mbase + rt * 16 + (lane >> 4) * 4 + r;
                xp[m * 512 + n] = (f16)(acc[rt][ct][r] + bias);
            }
        }
    }
}

// ---------------------------------------------------------------------------
// Phase 2: recurrence.  1 block (512 thr, 8 waves) per batch, 32 blocks.
//
// Register constraint (r5 post-mortem): 8-wave block => 256 unified regs/
// thread max.  Weights total 256 regs/thread, VALU-fed weights must be arch
// VGPRs => r5's 256-reg weight set spilled (latency-bound reloads, 2.2x).
//
// Round 6 split (fits the file; footprint ~= r0's which ran cleanly):
//   MFMA 256 cols  : wreg[32] (128 regs, AGPR-eligible B-operands),
//                    256 mfma/CU/step ~ 1241 cyc matrix pipe.
//   VALU 128 cols  : wv[16] (64 arch regs), 64 fdot2/lane.
//   LDS  128 cols  : staged once in 128 KiB LDS (lane-linear, conflict-free
//                    ds_read_b128), 64 fdot2/lane, 128 KB/step LDS stream.
//   One output col per thread (q-quarter split): 1 xp prefetch + 1 tanh each.
// ---------------------------------------------------------------------------
#define P2_LDS_BYTES (2 * HID * 2 + 8 * 16 * 4 * 16 * 8 * 2)  // 2048 + 131072

__global__ __launch_bounds__(512, 2) void rnn_kernel(
    const float* __restrict__ Whh, const f16* __restrict__ xp,
    f16* __restrict__ hfin)
{
    extern __shared__ __align__(16) char smem[];
    f16* hbuf0 = (f16*)smem;                 // 512
    f16* hbuf1 = hbuf0 + HID;                // 512
    f16* wlds  = hbuf1 + HID;                // [wave][kf][q][c_in] f16x8

    const int t = threadIdx.x;
    const int wave = t >> 6, lane = t & 63;
    const int b = blockIdx.x;

    const int c_in = lane & 15;              // fragment column
    const int q    = lane >> 4;              // k-quarter 0..3
    const int k8   = q * 8;                  // fragment k base

    // ---- MFMA weights: 2 tiles/wave, cols n = wave*32 + tt*16 + c_in ----
    f16x8 wreg[32];
#pragma unroll
    for (int tt = 0; tt < 2; tt++) {
        const float* wrow = Whh + (size_t)(wave * 32 + tt * 16 + c_in) * 512;
#pragma unroll
        for (int kf = 0; kf < 16; kf++) {
            float4 w0 = *(const float4*)(wrow + kf * 32 + k8);
            float4 w1 = *(const float4*)(wrow + kf * 32 + k8 + 4);
            f16x8 h;
            h[0] = (f16)w0.x; h[1] = (f16)w0.y; h[2] = (f16)w0.z; h[3] = (f16)w0.w;
            h[4] = (f16)w1.x; h[5] = (f16)w1.y; h[6] = (f16)w1.z; h[7] = (f16)w1.w;
            wreg[tt * 16 + kf] = h;
        }
    }
    // ---- VALU-reg col: n = 256 + wave*16 + c_in, this lane's k-quarter ----
    const int nr = 256 + wave * 16 + c_in;
    f16x8 wv[16];
#pragma unroll
    for (int kf = 0; kf < 16; kf++) {
        const float* p = Whh + (size_t)nr * 512 + kf * 32 + k8;
        float4 w0 = *(const float4*)p;
        float4 w1 = *(const float4*)(p + 4);
        f16x8 h;
        h[0] = (f16)w0.x; h[1] = (f16)w0.y; h[2] = (f16)w0.z; h[3] = (f16)w0.w;
        h[4] = (f16)w1.x; h[5] = (f16)w1.y; h[6] = (f16)w1.z; h[7] = (f16)w1.w;
        wv[kf] = h;
    }
    // ---- LDS col: n = 384 + wave*16 + c_in -> wlds, lane-linear layout ----
    // offset(wave,kf,q,c_in) = wave*8192 + kf*512 + (q*16 + c_in)*8 f16;
    // per (wave,kf) a wave's 64 lanes read a contiguous 1 KiB => conflict-free
    const int nl = 384 + wave * 16 + c_in;
    {
        const float* wrow = Whh + (size_t)nl * 512;
#pragma unroll
        for (int kf = 0; kf < 16; kf++) {
            float4 w0 = *(const float4*)(wrow + kf * 32 + k8);
            float4 w1 = *(const float4*)(wrow + kf * 32 + k8 + 4);
            f16x8 h;
            h[0] = (f16)w0.x; h[1] = (f16)w0.y; h[2] = (f16)w0.z; h[3] = (f16)w0.w;
            h[4] = (f16)w1.x; h[5] = (f16)w1.y; h[6] = (f16)w1.z; h[7] = (f16)w1.w;
            *(f16x8*)&wlds[wave * 8192 + kf * 512 + (q * 16 + c_in) * 8] = h;
        }
    }

    hbuf0[t & (HID - 1)] = (f16)0.f;         // h0 = 0
    __syncthreads();

    // one output column per thread, quarter-split
    const int out_col = (q == 0) ? (wave * 32 + c_in)
                      : (q == 1) ? (wave * 32 + 16 + c_in)
                      : (q == 2) ? nr : nl;
    const size_t xbase = (size_t)b * SEQL * 512;
    const int wbase = wave * 8192 + (q * 16 + c_in) * 8;

    float xv = (float)xp[xbase + out_col];   // dist-1 float prefetch (r0 pattern)
    for (int s = 0; s < NSTEP; s++) {
        const f16* cur = (s & 1) ? hbuf1 : hbuf0;
        f16*       nxt = (s & 1) ? hbuf0 : hbuf1;
        int sn = (s + 1 < NSTEP) ? s + 1 : s;
        float xv_next = (float)xp[xbase + (size_t)sn * 512 + out_col];

        f32x4 acc0 = (f32x4){0.f, 0.f, 0.f, 0.f}, acc1 = acc0;
        float sr = 0.f, sl = 0.f;
#pragma unroll
        for (int kf = 0; kf < 16; kf++) {
            f16x8 av = *(const f16x8*)&cur[kf * 32 + k8];          // broadcast
            f16x8 bl = *(const f16x8*)&wlds[wbase + kf * 512];     // lane-linear
            acc0 = __builtin_amdgcn_mfma_f32_16x16x32_f16(av, wreg[kf],      acc0, 0, 0, 0);
            acc1 = __builtin_amdgcn_mfma_f32_16x16x32_f16(av, wreg[16 + kf], acc1, 0, 0, 0);
            RNN_DOT8(av, wv[kf], sr);
            RNN_DOT8(av, bl, sl);
        }
        // reduce VALU k-partials across the 4 lane-quarters (bits 4,5)
        sr += __shfl_xor(sr, 16, 64); sr += __shfl_xor(sr, 32, 64);
        sl += __shfl_xor(sl, 16, 64); sl += __shfl_xor(sl, 32, 64);

        // MFMA D rows all identical (A rows = h); any lane's reg 0 is the col
        float v = (q == 0) ? acc0[0] : (q == 1) ? acc1[0] : (q == 2) ? sr : sl;
        v += xv;
        // tanh(v) = 1 - 2/(exp(2v)+1)   (saturates correctly, no NaN)
        float e = __expf(2.f * v);
        v = 1.f - 2.f / (e + 1.f);
        nxt[out_col] = (f16)v;
        xv = xv_next;
        __syncthreads();
    }
    // NSTEP even -> final h sits in hbuf0
    hfin[(size_t)b * 512 + t] = hbuf0[t & (HID - 1)];
}

// ---------------------------------------------------------------------------
// Phase 3: out[b][o] = sum_k h[b][k] * Wfc[o][k] + bfc[o]  (fp32 out)
// 32 blocks x 16 o-slice, 256 threads; h staged in padded LDS.
// ---------------------------------------------------------------------------
#define P3_HS 520  // padded stride (f16); 1040B is 16B-aligned

__global__ __launch_bounds__(256, 2) void fc_kernel(
    const f16* __restrict__ hfin, const float* __restrict__ Wfc,
    const float* __restrict__ bfc, float* __restrict__ out)
{
    __shared__ __align__(16) f16 hs[BATCH * P3_HS];
    const int t = threadIdx.x;
    // stage h (coalesced 2B loads, scattered padded LDS writes — one-time)
    for (int i = 0; i < 64; i++) {
        int e = i * 256 + t;                 // 0..16383
        hs[(e >> 9) * P3_HS + (e & 511)] = hfin[e];
    }
    __syncthreads();

    const int bidx = t & 31;
    const int oi = t >> 5;                   // 0..7
    const int o0 = blockIdx.x * 16;
    const int oA = o0 + oi, oB = o0 + oi + 8;
    const float* wA = Wfc + (size_t)oA * 512;
    const float* wB = Wfc + (size_t)oB * 512;

    float sA = 0.f, sB = 0.f;
#pragma unroll 4
    for (int kb = 0; kb < 64; kb++) {
        f16x8 hv = *(const f16x8*)&hs[bidx * P3_HS + kb * 8];
        float4 wa0 = *(const float4*)(wA + kb * 8);
        float4 wa1 = *(const float4*)(wA + kb * 8 + 4);
        float4 wb0 = *(const float4*)(wB + kb * 8);
        float4 wb1 = *(const float4*)(wB + kb * 8 + 4);
        float h0 = (float)hv[0], h1 = (float)hv[1], h2 = (float)hv[2], h3 = (float)hv[3];
        float h4 = (float)hv[4], h5 = (float)hv[5], h6 = (float)hv[6], h7 = (float)hv[7];
        sA += wa0.x*h0 + wa0.y*h1 + wa0.z*h2 + wa0.w*h3 + wa1.x*h4 + wa1.y*h5 + wa1.z*h6 + wa1.w*h7;
        sB += wb0.x*h0 + wb0.y*h1 + wb0.z*h2 + wb0.w*h3 + wb1.x*h4 + wb1.y*h5 + wb1.z*h6 + wb1.w*h7;
    }
    out[(size_t)bidx * 512 + oA] = sA + bfc[oA];
    out[(size_t)bidx * 512 + oB] = sB + bfc[oB];
}

// ---------------------------------------------------------------------------
extern "C" void kernel_launch(void* const* d_in, const int* in_sizes, int n_in,
                              void* d_out, int out_size, void* d_ws, size_t ws_size,
                              hipStream_t stream) {
    const float* x    = (const float*)d_in[0];
    const float* Wxh  = (const float*)d_in[1];
    const float* bxh  = (const float*)d_in[2];
    const float* Whh  = (const float*)d_in[3];
    const float* bhh  = (const float*)d_in[4];
    const float* bh   = (const float*)d_in[5];
    const float* Wfc  = (const float*)d_in[6];
    const float* bfc  = (const float*)d_in[7];
    float* outp = (float*)d_out;

    f16* xp   = (f16*)d_ws;                                   // 64 MiB
    f16* hfin = (f16*)((char*)d_ws + (size_t)BATCH * SEQL * 512 * 2);

    // allow 130 KiB dynamic LDS for the rnn kernel (idempotent, capture-safe)
    hipFuncSetAttribute((const void*)rnn_kernel,
                        hipFuncAttributeMaxDynamicSharedMemorySize, 160 * 1024);

    xproj_kernel<<<(BATCH * SEQL) / 64, 256, 0, stream>>>(x, Wxh, bxh, bhh, bh, xp);
    rnn_kernel<<<BATCH, 512, P2_LDS_BYTES, stream>>>(Whh, xp, hfin);
    fc_kernel<<<32, 256, 0, stream>>>(hfin, Wfc, bfc, outp);
}